// Round 7
// baseline (207.991 us; speedup 1.0000x reference)
//
#include <hip/hip_runtime.h>
#include <stdint.h>

// ODE sampler (VP-SDE probability-flow, RK4, T=50) for B=2048, D=16, H=256.
// tr(J) analytic: tr = -0.5*beta*(D + sum_k (1-h_k^2)*c_k).
//
// R7 vs R6 (125us kernel, VALUBusy 72% = 551 cyc/wave-Feval vs ~264 static):
// the gap matches v_dot2_f32_f16 being slower than full rate. Replace ALL
// dot work with v_pk_fma_f32 (<2 x float> fma, full-rate packed fp32):
//  - phase-1: 32 pk_fma (u for lane's 4 k), weights fp32 pairs in regs
//  - phase-2: 4 outputs/lane x 16 k/lane (16-lane groups = DPP rows):
//    32 pk_fma, 4 b128 fp32 h-reads, 4-level DPP row reduce
//    (0xB1 ^1, 0x4E ^2, half-mirror, mirror), old=src (no zero-mov)
//  - fp32 everywhere -> absmax should drop ~25x
//  - h chunks: 16 dwords + 4 pad (CH=20): write quads balanced 4/4,
//    read quads (5*c4+m)%8 2-way aliased = free (m136)
// Kept from R6: one wave per sample, zero barriers, readlane x-broadcast
// (16 readlanes), exp2-prescaled tanh, deferred ldj.

typedef float v2f __attribute__((ext_vector_type(2)));

__device__ __forceinline__ v2f fma2(v2f a, v2f b, v2f c) {
    return __builtin_elementwise_fma(a, b, c);
}

// DPP add across a 16-lane row; old = src (valid for full-row perms).
#define DPP_X1  0xB1    // quad_perm [1,0,3,2]  (^1)
#define DPP_X2  0x4E    // quad_perm [2,3,0,1]  (^2)
#define DPP_HM  0x141   // row_half_mirror      (quad <-> quad^1)
#define DPP_MIR 0x140   // row_mirror           (half <-> half)
template <int CTRL>
__device__ __forceinline__ float dpp_add(float x) {
    const int xi = __builtin_bit_cast(int, x);
    const int v  = __builtin_amdgcn_update_dpp(xi, xi, CTRL, 0xF, 0xF, false);
    return x + __builtin_bit_cast(float, v);
}

__device__ __forceinline__ float rlf(float v, int l) {
    return __builtin_bit_cast(
        float, __builtin_amdgcn_readlane(__builtin_bit_cast(int, v), l));
}

#define Bn 2048
#define Dn 16
#define Hn 256
#define Tn 50
#define CH 20            // dwords per 16-k h chunk: 16 data + 4 pad

__global__ __launch_bounds__(64) void ode_kernel(
    const float* __restrict__ x_in,   // [B][D]
    const float* __restrict__ W1,     // [D][H]
    const float* __restrict__ b1v,    // [H]
    const float* __restrict__ wtv,    // [H]
    const float* __restrict__ W2,     // [H][D]
    const float* __restrict__ b2v,    // [D]
    float* __restrict__ out)          // xf[B*D] | ldjf[B] | xt[T*B*D]
{
    __shared__ __align__(16) float h_lds[16 * CH];   // fp32 h, chunk-padded

    const int L  = threadIdx.x;       // one wave per block = one sample
    const int iq = L >> 4;            // i-quad group (DPP row)
    const int c4 = L & 15;            // phase-2 k-chunk (16 k)
    const int i0 = 4 * iq;
    const int k0 = 4 * L;             // phase-1: this lane's 4 hidden units
    const int gs = blockIdx.x;

    const float K2 = 2.88539008f;     // 2*log2(e): exp2(K2*u) = e^{2u}

    // ---- one-time init: weights fp32 into registers ----
    v2f w1v[4][8];                    // [q][j] = K2*{W1[2j][k0+q], W1[2j+1][k0+q]}
    float b1k[4], wtk[4], ck[4];
    #pragma unroll
    for (int q = 0; q < 4; ++q) {
        const int k = k0 + q;
        #pragma unroll
        for (int j = 0; j < 8; ++j) {
            v2f v;
            v.x = K2 * W1[(2 * j)     * Hn + k];
            v.y = K2 * W1[(2 * j + 1) * Hn + k];
            w1v[q][j] = v;
        }
        b1k[q] = K2 * b1v[k];
        wtk[q] = K2 * wtv[k];
        float s = 0.f;
        #pragma unroll
        for (int ii = 0; ii < 16; ++ii)
            s = fmaf(W1[ii * Hn + k], W2[k * Dn + ii], s);
        ck[q] = s;
    }
    v2f w2v[4][8];                    // [q][n] = {W2[16c4+2n][i0+q], W2[16c4+2n+1][i0+q]}
    #pragma unroll
    for (int q = 0; q < 4; ++q)
        #pragma unroll
        for (int n = 0; n < 8; ++n) {
            v2f v;
            v.x = W2[(16 * c4 + 2 * n)     * Dn + i0 + q];
            v.y = W2[(16 * c4 + 2 * n + 1) * Dn + i0 + q];
            w2v[q][n] = v;
        }
    float b2q[4];
    #pragma unroll
    for (int q = 0; q < 4; ++q) b2q[q] = b2v[i0 + q];

    // lane state: 4 components x[i0..i0+3] (replicated across the 16-lane row)
    const float4 xld = *(const float4*)(x_in + gs * Dn + i0);
    float x0 = xld.x, x1 = xld.y, x2 = xld.z, x3 = xld.w;
    float ldjl = 0.f, wbsum = 0.f;

    float* xf_out  = out;
    float* ldj_out = out + (size_t)Bn * Dn;
    float* xt_ptr  = out + (size_t)Bn * Dn + Bn + gs * Dn + i0;

    if (c4 == 0) *(float4*)xt_ptr = make_float4(x0, x1, x2, x3);   // xt[0]
    xt_ptr += Bn * Dn;

    // x-broadcast: 16 readlanes -> wave-uniform v2f pairs xv[j] = {x_2j, x_2j+1}
    v2f xv[8];
    auto bcast = [&](float e0, float e1, float e2, float e3) {
        #pragma unroll
        for (int j = 0; j < 4; ++j) {
            v2f a, b;
            a.x = rlf(e0, 16 * j);  a.y = rlf(e1, 16 * j);
            b.x = rlf(e2, 16 * j);  b.y = rlf(e3, 16 * j);
            xv[2 * j]     = a;      // {x[4j],   x[4j+1]}
            xv[2 * j + 1] = b;      // {x[4j+2], x[4j+3]}
        }
    };

    auto Feval = [&](float e0, float e1, float e2, float e3, float tt, float wgt,
                     float& d0, float& d1, float& d2, float& d3) {
        // ---- phase 1: u for this lane's 4 hidden units (pk_fma_f32) ----
        v2f a0 = {0.f, 0.f}, a1 = {0.f, 0.f}, a2 = {0.f, 0.f}, a3 = {0.f, 0.f};
        #pragma unroll
        for (int j = 0; j < 8; ++j) {
            a0 = fma2(xv[j], w1v[0][j], a0);
            a1 = fma2(xv[j], w1v[1][j], a1);
            a2 = fma2(xv[j], w1v[2][j], a2);
            a3 = fma2(xv[j], w1v[3][j], a3);
        }
        const float u0 = fmaf(tt, wtk[0], b1k[0]) + (a0.x + a0.y);
        const float u1 = fmaf(tt, wtk[1], b1k[1]) + (a1.x + a1.y);
        const float u2 = fmaf(tt, wtk[2], b1k[2]) + (a2.x + a2.y);
        const float u3 = fmaf(tt, wtk[3], b1k[3]) + (a3.x + a3.y);
        // u prescaled: exp2(u) = e^{2u_true}; tanh = 1 - 2/(E+1), saturation exact
        const float h0 = fmaf(-2.f, __builtin_amdgcn_rcpf(__builtin_amdgcn_exp2f(u0) + 1.f), 1.f);
        const float h1 = fmaf(-2.f, __builtin_amdgcn_rcpf(__builtin_amdgcn_exp2f(u1) + 1.f), 1.f);
        const float h2 = fmaf(-2.f, __builtin_amdgcn_rcpf(__builtin_amdgcn_exp2f(u2) + 1.f), 1.f);
        const float h3 = fmaf(-2.f, __builtin_amdgcn_rcpf(__builtin_amdgcn_exp2f(u3) + 1.f), 1.f);
        *(float4*)&h_lds[CH * (L >> 2) + 4 * (L & 3)] = make_float4(h0, h1, h2, h3);

        // trace partial + deferred ldj (fills the DS write->read bubble)
        const float gl = (fmaf(-h0 * h0, ck[0], ck[0]) + fmaf(-h1 * h1, ck[1], ck[1]))
                       + (fmaf(-h2 * h2, ck[2], ck[2]) + fmaf(-h3 * h3, ck[3], ck[3]));
        const float beta = fmaf(tt, 19.9f, 0.1f);
        const float nhb  = -0.5f * beta;
        const float wb   = wgt * nhb;
        ldjl  = fmaf(wb, gl, ldjl);
        wbsum += wb;

        asm volatile("" ::: "memory");     // keep h write above the reads

        // ---- phase 2: 4 outputs over this lane's 16 k (pk_fma_f32) ----
        const float* hb = &h_lds[CH * c4];
        v2f s0 = {0.f, 0.f}, s1 = {0.f, 0.f}, s2 = {0.f, 0.f}, s3 = {0.f, 0.f};
        #pragma unroll
        for (int m = 0; m < 4; ++m) {
            const float4 hp = *(const float4*)(hb + 4 * m);
            v2f hA; hA.x = hp.x; hA.y = hp.y;
            v2f hB; hB.x = hp.z; hB.y = hp.w;
            s0 = fma2(hA, w2v[0][2 * m], s0);  s0 = fma2(hB, w2v[0][2 * m + 1], s0);
            s1 = fma2(hA, w2v[1][2 * m], s1);  s1 = fma2(hB, w2v[1][2 * m + 1], s1);
            s2 = fma2(hA, w2v[2][2 * m], s2);  s2 = fma2(hB, w2v[2][2 * m + 1], s2);
            s3 = fma2(hA, w2v[3][2 * m], s3);  s3 = fma2(hB, w2v[3][2 * m + 1], s3);
        }
        float t0 = s0.x + s0.y, t1 = s1.x + s1.y;
        float t2 = s2.x + s2.y, t3 = s3.x + s3.y;
        // 16-lane row reduce on the VALU pipe (4 DPP levels)
        t0 = dpp_add<DPP_X1 >(t0); t1 = dpp_add<DPP_X1 >(t1);
        t2 = dpp_add<DPP_X1 >(t2); t3 = dpp_add<DPP_X1 >(t3);
        t0 = dpp_add<DPP_X2 >(t0); t1 = dpp_add<DPP_X2 >(t1);
        t2 = dpp_add<DPP_X2 >(t2); t3 = dpp_add<DPP_X2 >(t3);
        t0 = dpp_add<DPP_HM >(t0); t1 = dpp_add<DPP_HM >(t1);
        t2 = dpp_add<DPP_HM >(t2); t3 = dpp_add<DPP_HM >(t3);
        t0 = dpp_add<DPP_MIR>(t0); t1 = dpp_add<DPP_MIR>(t1);
        t2 = dpp_add<DPP_MIR>(t2); t3 = dpp_add<DPP_MIR>(t3);

        d0 = nhb * (e0 + t0 + b2q[0]);
        d1 = nhb * (e1 + t1 + b2q[1]);
        d2 = nhb * (e2 + t2 + b2q[2]);
        d3 = nhb * (e3 + t3 + b2q[3]);
    };

    const float t_lo = 1e-3f;
    const float dt   = (1.0f - 1e-3f) / (float)(Tn - 1);
    const float hh   = dt;
    const float w1w  = hh * (1.f / 6.f);
    const float w2w  = hh * (2.f / 6.f);

    bcast(x0, x1, x2, x3);
    for (int j = 0; j < Tn - 1; ++j) {
        const float t0 = fmaf((float)j, dt, t_lo);
        const float tm = t0 + 0.5f * hh;
        const float t1 = t0 + hh;
        float k1[4], k2[4], k3[4], k4[4];

        Feval(x0, x1, x2, x3, t0, w1w, k1[0], k1[1], k1[2], k1[3]);
        float e0 = fmaf(0.5f * hh, k1[0], x0), e1 = fmaf(0.5f * hh, k1[1], x1);
        float e2 = fmaf(0.5f * hh, k1[2], x2), e3 = fmaf(0.5f * hh, k1[3], x3);
        bcast(e0, e1, e2, e3);
        Feval(e0, e1, e2, e3, tm, w2w, k2[0], k2[1], k2[2], k2[3]);
        e0 = fmaf(0.5f * hh, k2[0], x0); e1 = fmaf(0.5f * hh, k2[1], x1);
        e2 = fmaf(0.5f * hh, k2[2], x2); e3 = fmaf(0.5f * hh, k2[3], x3);
        bcast(e0, e1, e2, e3);
        Feval(e0, e1, e2, e3, tm, w2w, k3[0], k3[1], k3[2], k3[3]);
        e0 = fmaf(hh, k3[0], x0); e1 = fmaf(hh, k3[1], x1);
        e2 = fmaf(hh, k3[2], x2); e3 = fmaf(hh, k3[3], x3);
        bcast(e0, e1, e2, e3);
        Feval(e0, e1, e2, e3, t1, w1w, k4[0], k4[1], k4[2], k4[3]);

        x0 = fmaf(w1w, k1[0] + 2.f * (k2[0] + k3[0]) + k4[0], x0);
        x1 = fmaf(w1w, k1[1] + 2.f * (k2[1] + k3[1]) + k4[1], x1);
        x2 = fmaf(w1w, k1[2] + 2.f * (k2[2] + k3[2]) + k4[2], x2);
        x3 = fmaf(w1w, k1[3] + 2.f * (k2[3] + k3[3]) + k4[3], x3);
        if (c4 == 0) *(float4*)xt_ptr = make_float4(x0, x1, x2, x3);
        xt_ptr += Bn * Dn;
        bcast(x0, x1, x2, x3);
    }

    if (c4 == 0) *(float4*)(xf_out + gs * Dn + i0) = make_float4(x0, x1, x2, x3);

    // ldj: fold constant D-term (16/64 per lane), one-time full-wave butterfly
    ldjl = fmaf(0.25f, wbsum, ldjl);
    #pragma unroll
    for (int off = 1; off < 64; off <<= 1)
        ldjl += __shfl_xor(ldjl, off);
    if (L == 0) ldj_out[gs] = ldjl;
}

extern "C" void kernel_launch(void* const* d_in, const int* in_sizes, int n_in,
                              void* d_out, int out_size, void* d_ws, size_t ws_size,
                              hipStream_t stream) {
    const float* x  = (const float*)d_in[0];
    const float* W1 = (const float*)d_in[1];
    const float* b1 = (const float*)d_in[2];
    const float* wt = (const float*)d_in[3];
    const float* W2 = (const float*)d_in[4];
    const float* b2 = (const float*)d_in[5];
    (void)in_sizes; (void)n_in; (void)out_size; (void)d_ws; (void)ws_size;
    ode_kernel<<<Bn, 64, 0, stream>>>(x, W1, b1, wt, W2, b2, (float*)d_out);
}